// Round 2
// baseline (842.002 us; speedup 1.0000x reference)
//
#include <hip/hip_runtime.h>
#include <stdint.h>

#define HID 768
#define NB  128

typedef _Float16 half8    __attribute__((ext_vector_type(8)));
typedef __fp16   fp16x2   __attribute__((ext_vector_type(2)));
typedef float    float4_t __attribute__((ext_vector_type(4)));
typedef float    f32x16   __attribute__((ext_vector_type(16)));

// ws layout: fp16 hi plane [24 i32-tile][48 k16-tile][64 lane][8 halves], then lo plane.
// Lane l of tile (i32,k16) holds op[i32*32 + (l&31)][k16*16 + (l>>5)*8 .. +8]
// == the B-operand fragment of mfma_f32_32x32x16_f16.
#define OP_TILES (24 * 48)
#define OP_PLANE ((size_t)OP_TILES * 64 * 8)   // 1.18 MB per plane

__device__ __forceinline__ void convert8(const float4_t a, const float4_t b,
                                         half8& h, half8& l)
{
    fp16x2 h01 = __builtin_amdgcn_cvt_pkrtz(a[0], a[1]);
    fp16x2 h23 = __builtin_amdgcn_cvt_pkrtz(a[2], a[3]);
    fp16x2 h45 = __builtin_amdgcn_cvt_pkrtz(b[0], b[1]);
    fp16x2 h67 = __builtin_amdgcn_cvt_pkrtz(b[2], b[3]);
    fp16x2 l01 = __builtin_amdgcn_cvt_pkrtz(a[0] - (float)h01[0], a[1] - (float)h01[1]);
    fp16x2 l23 = __builtin_amdgcn_cvt_pkrtz(a[2] - (float)h23[0], a[3] - (float)h23[1]);
    fp16x2 l45 = __builtin_amdgcn_cvt_pkrtz(b[0] - (float)h45[0], b[1] - (float)h45[1]);
    fp16x2 l67 = __builtin_amdgcn_cvt_pkrtz(b[2] - (float)h67[0], b[3] - (float)h67[1]);
    h = (half8){(_Float16)h01[0], (_Float16)h01[1], (_Float16)h23[0], (_Float16)h23[1],
                (_Float16)h45[0], (_Float16)h45[1], (_Float16)h67[0], (_Float16)h67[1]};
    l = (half8){(_Float16)l01[0], (_Float16)l01[1], (_Float16)l23[0], (_Float16)l23[1],
                (_Float16)l45[0], (_Float16)l45[1], (_Float16)l67[0], (_Float16)l67[1]};
}

// Pre-split operator into fp16 hi/lo in 32x32 B-fragment order.
__global__ __launch_bounds__(256)
void split_op(const float* __restrict__ OP, _Float16* __restrict__ ws)
{
    const int g    = blockIdx.x * 256 + threadIdx.x;
    const int tile = g >> 6, lane = g & 63;
    const int i32t = tile / 48, k16 = tile % 48;
    const int i = i32t * 32 + (lane & 31);
    const int k = k16 * 16 + (lane >> 5) * 8;
    const float4_t a = *(const float4_t*)(OP + (size_t)i * HID + k);
    const float4_t b = *(const float4_t*)(OP + (size_t)i * HID + k + 4);
    half8 h, l;
    convert8(a, b, h, l);
    *(half8*)(ws + (size_t)(tile * 64 + lane) * 8) = h;
    *(half8*)(ws + OP_PLANE + (size_t)(tile * 64 + lane) * 8) = l;
}

// Untracked global load: compiler's waitcnt scoreboard cannot see it, so it
// cannot insert a defensive vmcnt(0); completion is enforced by the manual
// counted s_waitcnt vmcnt(4) + sched_barrier(0) at each step top (T4 pattern).
__device__ __forceinline__ half8 gld16(const _Float16* p)
{
    half8 d;
    asm volatile("global_load_dwordx4 %0, %1, off" : "=&v"(d) : "v"(p));
    return d;
}

// D[b,i] = sum_j op[i,j] * P[j,i],  P = X_b @ op^T (k-reduction).
// Counted-vmcnt pipeline (T3+T4): LDS triple-buffer, X DMA'd 2 steps ahead via
// global_load_lds (linear dest, conflict-free); B fragments double-buffered in
// regs, asm-loaded 1 step ahead from L2-resident opws. One raw s_barrier/step,
// vmcnt never drained to 0 in the main loop (except compiler waits at the 6
// fold steps). Per-step VMEM issue: 8 B-loads then 4 DMAs; queue at step top =
// [DMA(t):4, B(t):8, DMA(t+1):4] -> s_waitcnt vmcnt(4) retires exactly
// DMA(t)+B(t), leaving DMA(t+1) in flight.
__global__ __launch_bounds__(256, 3)
void diag_quad_kernel(const float* __restrict__ X, const float* __restrict__ OP,
                      const _Float16* __restrict__ opws, float* __restrict__ out)
{
    __shared__ __align__(16) float Abuf[3][4096];   // 3 x 16 KB
    __shared__ float Dred[2][128];

    const int idx  = blockIdx.x;
    const int xcd  = idx & 7, slot = idx >> 3;
    const int b    = xcd * 16 + slot / 6;
    const int it   = slot % 6;
    const int i0   = it * 128;
    const float* Xb = X + (size_t)b * HID * HID;

    const int tid  = threadIdx.x;
    const int lane = tid & 63;
    const int wave = tid >> 6;
    const int wj   = wave & 1;      // j-half (64 rows)
    const int wi   = wave >> 1;     // i-half (64 cols)
    const int l5   = lane >> 5;
    const int m32  = lane & 31;

    const int srow = wave * 32 + m32;   // DMA: wave w stages rows w*32..+31
    const int scol = l5 * 4;
    const int i32base = it * 4 + wi * 2;

    float p0 = 0.f, p1 = 0.f;
    half8 bhA[2][2], blA[2][2], bhB[2][2], blB[2][2];
    f32x16 acc[2][2];

#define STAGE4(bi, jtile, kstep)                                                       \
    {                                                                                  \
        const float* _s = Xb + (size_t)((jtile) * 128 + srow) * HID + (kstep) * 32 + scol; \
        _Pragma("unroll")                                                              \
        for (int _i = 0; _i < 4; ++_i)                                                 \
            __builtin_amdgcn_global_load_lds(                                          \
                (const __attribute__((address_space(1))) uint32_t*)(_s + _i * 8),      \
                (__attribute__((address_space(3))) uint32_t*)(&Abuf[0][0] + (bi) * 4096 + (wave * 4 + _i) * 256), \
                16, 0, 0);                                                             \
    }

#define LOADB(BH, BL, kss)                                                             \
    {                                                                                  \
        _Pragma("unroll")                                                              \
        for (int _tj = 0; _tj < 2; ++_tj) {                                            \
            _Pragma("unroll")                                                          \
            for (int _kh = 0; _kh < 2; ++_kh) {                                        \
                const size_t _o = ((size_t)((i32base + _tj) * 48 + (kss) * 2 + _kh)) * 512 \
                                  + (size_t)lane * 8;                                  \
                BH[_tj][_kh] = gld16(opws + _o);                                       \
                BL[_tj][_kh] = gld16(opws + OP_PLANE + _o);                            \
            }                                                                          \
        }                                                                              \
    }

#define ZACC()                                                                         \
    {                                                                                  \
        _Pragma("unroll") for (int _a = 0; _a < 2; ++_a)                               \
        _Pragma("unroll") for (int _b = 0; _b < 2; ++_b)                               \
        _Pragma("unroll") for (int _e = 0; _e < 16; ++_e) acc[_a][_b][_e] = 0.f;       \
    }

#define COMPUTE(bi, BH, BL)                                                            \
    {                                                                                  \
        const float* Ab = &Abuf[0][0] + (bi) * 4096;                                   \
        _Pragma("unroll")                                                              \
        for (int _ti = 0; _ti < 2; ++_ti) {                                            \
            const int _rt = wj * 2 + _ti;                                              \
            _Pragma("unroll")                                                          \
            for (int _kh = 0; _kh < 2; ++_kh) {                                        \
                const int _fb = ((_rt * 2 + _kh) * 128 + l5 * 64 + m32) * 4;           \
                const float4_t _x0 = *(const float4_t*)&Ab[_fb];                       \
                const float4_t _x1 = *(const float4_t*)&Ab[_fb + 128];                 \
                half8 _ah, _al;                                                        \
                convert8(_x0, _x1, _ah, _al);                                          \
                _Pragma("unroll")                                                      \
                for (int _tj = 0; _tj < 2; ++_tj) {                                    \
                    acc[_ti][_tj] = __builtin_amdgcn_mfma_f32_32x32x16_f16(_ah, BH[_tj][_kh], acc[_ti][_tj], 0, 0, 0); \
                    acc[_ti][_tj] = __builtin_amdgcn_mfma_f32_32x32x16_f16(_al, BH[_tj][_kh], acc[_ti][_tj], 0, 0, 0); \
                    acc[_ti][_tj] = __builtin_amdgcn_mfma_f32_32x32x16_f16(_ah, BL[_tj][_kh], acc[_ti][_tj], 0, 0, 0); \
                }                                                                      \
            }                                                                          \
        }                                                                              \
    }

#define FOLD()                                                                         \
    {                                                                                  \
        const int _j0f = jt * 128;                                                     \
        _Pragma("unroll")                                                              \
        for (int _tj = 0; _tj < 2; ++_tj) {                                            \
            const int _ia = i0 + wi * 64 + _tj * 32 + m32;                             \
            float _s = 0.f;                                                            \
            _Pragma("unroll")                                                          \
            for (int _ti = 0; _ti < 2; ++_ti) {                                        \
                const int _jb = _j0f + wj * 64 + _ti * 32 + l5 * 4;                    \
                _Pragma("unroll")                                                      \
                for (int _r2 = 0; _r2 < 4; ++_r2) {                                    \
                    const float4_t _ov = *(const float4_t*)(OP + (size_t)_ia * HID + _jb + _r2 * 8); \
                    _s += acc[_ti][_tj][_r2 * 4 + 0] * _ov[0]                          \
                        + acc[_ti][_tj][_r2 * 4 + 1] * _ov[1]                          \
                        + acc[_ti][_tj][_r2 * 4 + 2] * _ov[2]                          \
                        + acc[_ti][_tj][_r2 * 4 + 3] * _ov[3];                         \
                }                                                                      \
            }                                                                          \
            if (_tj == 0) p0 += _s; else p1 += _s;                                     \
        }                                                                              \
    }

    // prologue: establish queue [DMA(0), B(0), DMA(1)]
    int jt = 0, ks = 0, bufi = 0;
    STAGE4(0, 0, 0);
    __builtin_amdgcn_sched_barrier(0);
    LOADB(bhA, blA, 0);
    __builtin_amdgcn_sched_barrier(0);
    STAGE4(1, 0, 1);
    __builtin_amdgcn_sched_barrier(0);

#define STEPBODY(BCH, BCL, BNH, BNL)                                                   \
    {                                                                                  \
        int _ksb = ks + 1; if (_ksb >= 24) _ksb = 0;         /* B addr: ks-only */     \
        int _ksd = ks + 2, _jtd = jt;                                                  \
        if (_ksd >= 24) { _ksd -= 24; _jtd = jt + 1; }                                 \
        if (_jtd >= 6) _jtd = 0;                             /* tail wrap (dummy) */   \
        int _bufd = bufi + 2; if (_bufd >= 3) _bufd -= 3;                              \
        asm volatile("s_waitcnt vmcnt(4)" ::: "memory");     /* DMA(t)+B(t) done */    \
        __builtin_amdgcn_s_barrier();                        /* buf[t%3] published */  \
        __builtin_amdgcn_sched_barrier(0);                                             \
        LOADB(BNH, BNL, _ksb);                               /* B(t+1) */              \
        __builtin_amdgcn_sched_barrier(0);                                             \
        STAGE4(_bufd, _jtd, _ksd);                           /* DMA(t+2) */            \
        __builtin_amdgcn_sched_barrier(0);                                             \
        if (ks == 0) ZACC();                                                           \
        COMPUTE(bufi, BCH, BCL);                                                       \
        if (ks == 23) FOLD();                                                          \
        ++ks; if (ks == 24) { ks = 0; ++jt; }                                          \
        ++bufi; if (bufi == 3) bufi = 0;                                               \
    }

    for (int th = 0; th < 72; ++th) {
        STEPBODY(bhA, blA, bhB, blB);
        STEPBODY(bhB, blB, bhA, blA);
    }
#undef STEPBODY
#undef FOLD
#undef COMPUTE
#undef ZACC
#undef LOADB
#undef STAGE4

    // lanes l and l+32 hold disjoint j-subsets of the same i
    p0 += __shfl_xor(p0, 32);
    p1 += __shfl_xor(p1, 32);
    if (lane < 32) {
        Dred[wj][wi * 64 + lane]      = p0;
        Dred[wj][wi * 64 + 32 + lane] = p1;
    }
    __syncthreads();
    if (tid < 128)
        out[(size_t)b * HID + i0 + tid] = Dred[0][tid] + Dred[1][tid];
}

// in-place row softmax: 128 rows x 768
__global__ __launch_bounds__(768)
void softmax_rows(float* __restrict__ out)
{
    const int row = blockIdx.x;
    const int t = threadIdx.x;
    const int wave = t >> 6, lane = t & 63;
    __shared__ float redm[12];
    __shared__ float reds[12];

    float v = out[(size_t)row * HID + t];

    float m = v;
#pragma unroll
    for (int o = 32; o >= 1; o >>= 1) m = fmaxf(m, __shfl_xor(m, o));
    if (lane == 0) redm[wave] = m;
    __syncthreads();
    if (t == 0) {
        float mm = redm[0];
        for (int w = 1; w < 12; ++w) mm = fmaxf(mm, redm[w]);
        redm[0] = mm;
    }
    __syncthreads();
    m = redm[0];

    const float e = expf(v - m);
    float s = e;
#pragma unroll
    for (int o = 32; o >= 1; o >>= 1) s += __shfl_xor(s, o);
    if (lane == 0) reds[wave] = s;
    __syncthreads();
    if (t == 0) {
        float ss = 0.f;
        for (int w = 0; w < 12; ++w) ss += reds[w];
        reds[0] = ss;
    }
    __syncthreads();
    out[(size_t)row * HID + t] = e / reds[0];
}

extern "C" void kernel_launch(void* const* d_in, const int* in_sizes, int n_in,
                              void* d_out, int out_size, void* d_ws, size_t ws_size,
                              hipStream_t stream)
{
    const float* X  = (const float*)d_in[0];   // [128,768,768] fp32
    const float* OP = (const float*)d_in[1];   // [768,768] fp32
    float* out = (float*)d_out;                // [128,768] fp32
    _Float16* opws = (_Float16*)d_ws;          // 2.36 MB pre-split op

    hipLaunchKernelGGL(split_op, dim3(OP_TILES / 4), dim3(256), 0, stream, OP, opws);
    hipLaunchKernelGGL(diag_quad_kernel, dim3(NB * 6), dim3(256), 0, stream, X, OP, opws, out);
    hipLaunchKernelGGL(softmax_rows, dim3(NB), dim3(768), 0, stream, out);
}

// Round 3
// 711.782 us; speedup vs baseline: 1.1829x; 1.1829x over previous
//
#include <hip/hip_runtime.h>

#define HID 768
#define NB  128

typedef _Float16 half8   __attribute__((ext_vector_type(8)));
typedef __fp16   fp16x2  __attribute__((ext_vector_type(2)));
typedef float    float4_t __attribute__((ext_vector_type(4)));

// ws layout: fp16 hi plane [48 i-tile16][24 kstep][64 lane][8 halves], then lo plane.
#define OP_TILES (48 * 24)
#define OP_PLANE ((size_t)OP_TILES * 64 * 8)   // 1.18 MB per plane

// Pre-split operator into fp16 hi/lo, fragment-major (B-operand order).
__global__ __launch_bounds__(256)
void split_op(const float* __restrict__ OP, _Float16* __restrict__ ws)
{
    const int g    = blockIdx.x * 256 + threadIdx.x;
    const int tile = g >> 6, lane = g & 63;
    const int it16 = tile / 24, ks = tile % 24;
    const int i = it16 * 16 + (lane & 15);
    const int k = ks * 32 + (lane >> 4) * 8;
    const float4_t a = *(const float4_t*)(OP + (size_t)i * HID + k);
    const float4_t b = *(const float4_t*)(OP + (size_t)i * HID + k + 4);
    half8 h, l;
#pragma unroll
    for (int e = 0; e < 4; ++e) {
        _Float16 h0 = (_Float16)a[e]; h[e]     = h0; l[e]     = (_Float16)(a[e] - (float)h0);
        _Float16 h1 = (_Float16)b[e]; h[e + 4] = h1; l[e + 4] = (_Float16)(b[e] - (float)h1);
    }
    *(half8*)(ws + (size_t)(tile * 64 + lane) * 8) = h;
    *(half8*)(ws + OP_PLANE + (size_t)(tile * 64 + lane) * 8) = l;
}

__device__ __forceinline__ void convert8(const float4_t a, const float4_t b,
                                         half8& h, half8& l)
{
    // hi = RTZ pack (1 instr / 2 floats); lo = exact residual, RTZ-packed.
    fp16x2 h01 = __builtin_amdgcn_cvt_pkrtz(a[0], a[1]);
    fp16x2 h23 = __builtin_amdgcn_cvt_pkrtz(a[2], a[3]);
    fp16x2 h45 = __builtin_amdgcn_cvt_pkrtz(b[0], b[1]);
    fp16x2 h67 = __builtin_amdgcn_cvt_pkrtz(b[2], b[3]);
    fp16x2 l01 = __builtin_amdgcn_cvt_pkrtz(a[0] - (float)h01[0], a[1] - (float)h01[1]);
    fp16x2 l23 = __builtin_amdgcn_cvt_pkrtz(a[2] - (float)h23[0], a[3] - (float)h23[1]);
    fp16x2 l45 = __builtin_amdgcn_cvt_pkrtz(b[0] - (float)h45[0], b[1] - (float)h45[1]);
    fp16x2 l67 = __builtin_amdgcn_cvt_pkrtz(b[2] - (float)h67[0], b[3] - (float)h67[1]);
    h = (half8){(_Float16)h01[0], (_Float16)h01[1], (_Float16)h23[0], (_Float16)h23[1],
                (_Float16)h45[0], (_Float16)h45[1], (_Float16)h67[0], (_Float16)h67[1]};
    l = (half8){(_Float16)l01[0], (_Float16)l01[1], (_Float16)l23[0], (_Float16)l23[1],
                (_Float16)l45[0], (_Float16)l45[1], (_Float16)l67[0], (_Float16)l67[1]};
}

// D[b,i] = sum_j op[i,j] * P[j,i],  P = X_b @ op^T (k-reduction).
// Block: (b, 128 i) x 128-j tiles; wave: 64j x 64i, acc 4x4 (64 AGPR -> 3 blk/CU).
// A (X) staged in LDS fp16 hi/lo, fragment-major chunks.
// Staging lane map is LINEAR-IN-LANE (byte = 16*lane within a 1KB chunk):
//   task q, wave w -> chunk rt = q*4 + w; lane l -> row rt*16 + (l&15),
//   k-group l>>4.  ds_write_b128 offsets are contiguous across the wave ->
//   zero bank conflicts (was 4-way: 4.25e7 conflict cycles in R0 mapping).
// Fragment reads (also linear-in-lane) unchanged; layout function of
// (row, kgroup) identical to the verified R0 kernel.
__global__ __launch_bounds__(256, 3)
void diag_quad_kernel(const float* __restrict__ X, const float* __restrict__ OP,
                      const _Float16* __restrict__ opws, float* __restrict__ out)
{
    // chunk (rt,kg,m16): halves offset rt*512 + kg*128 + m16*8  (bytes x2)
    __shared__ __align__(16) _Float16 Ah[4096];
    __shared__ __align__(16) _Float16 Al[4096];
    __shared__ float Dred[2][128];

    // XCD swizzle: 6 i-tile blocks of a batch share an XCD (L2 reuse of X_b)
    const int idx  = blockIdx.x;
    const int xcd  = idx & 7, slot = idx >> 3;
    const int b    = xcd * 16 + slot / 6;
    const int it   = slot % 6;
    const int i0   = it * 128;
    const float* Xb = X + (size_t)b * HID * HID;

    const int tid  = threadIdx.x;
    const int lane = tid & 63;
    const int wave = tid >> 6;
    const int wj   = wave & 1;      // j-half (64 rows)
    const int wi   = wave >> 1;     // i-half (64 cols)
    const int m16  = lane & 15;
    const int kg   = lane >> 4;     // 0..3

    // staging (linear-in-lane): task 0 -> chunk wave, task 1 -> chunk 4+wave
    const int row0 = wave * 16 + m16;          // rows 0..63
    const int row1 = 64 + wave * 16 + m16;     // rows 64..127
    const int kgs  = kg;                       // k-group 0..3 (8 floats each)
    const int lds0 = wave * 512 + lane * 8;         // == wave*512 + kgs*128 + m16*8
    const int lds1 = (4 + wave) * 512 + lane * 8;

    const int fragoff  = kg * 128 + m16 * 8;     // + rt*512
    const int it16base = it * 8 + wi * 4;

    float p[4] = {0.f, 0.f, 0.f, 0.f};

    for (int jt = 0; jt < 6; ++jt) {
        const int j0 = jt * 128;
        float4_t acc[4][4];
#pragma unroll
        for (int a = 0; a < 4; ++a)
#pragma unroll
            for (int c = 0; c < 4; ++c) acc[a][c] = (float4_t){0.f, 0.f, 0.f, 0.f};

        for (int ks = 0; ks < 24; ++ks) {
            const int k0 = ks * 32;

            // B fragments straight from ws (L2) — issue early, no LDS dependency
            half8 bh[4], bl[4];
            const size_t obase = ((size_t)it16base * 24 + ks) * 512 + (size_t)lane * 8;
#pragma unroll
            for (int tj = 0; tj < 4; ++tj) {
                bh[tj] = *(const half8*)(opws + obase + (size_t)tj * 24 * 512);
                bl[tj] = *(const half8*)(opws + OP_PLANE + obase + (size_t)tj * 24 * 512);
            }

            // staging global loads (2 tasks x 32B)
            const float* s0 = Xb + (size_t)(j0 + row0) * HID + k0 + kgs * 8;
            const float* s1 = Xb + (size_t)(j0 + row1) * HID + k0 + kgs * 8;
            const float4_t a0 = *(const float4_t*)(s0);
            const float4_t a1 = *(const float4_t*)(s0 + 4);
            const float4_t b0 = *(const float4_t*)(s1);
            const float4_t b1 = *(const float4_t*)(s1 + 4);
            half8 h0, l0v, h1, l1v;
            convert8(a0, a1, h0, l0v);
            convert8(b0, b1, h1, l1v);

            __syncthreads();   // previous iteration's frag reads complete
            *(half8*)&Ah[lds0] = h0;
            *(half8*)&Al[lds0] = l0v;
            *(half8*)&Ah[lds1] = h1;
            *(half8*)&Al[lds1] = l1v;
            __syncthreads();

#pragma unroll
            for (int ti = 0; ti < 4; ++ti) {
                const int off = (wj * 4 + ti) * 512 + fragoff;
                const half8 ah = *(const half8*)&Ah[off];
                const half8 al = *(const half8*)&Al[off];
#pragma unroll
                for (int tj = 0; tj < 4; ++tj) {
                    acc[ti][tj] = __builtin_amdgcn_mfma_f32_16x16x32_f16(ah, bh[tj], acc[ti][tj], 0, 0, 0);
                    acc[ti][tj] = __builtin_amdgcn_mfma_f32_16x16x32_f16(al, bh[tj], acc[ti][tj], 0, 0, 0);
                    acc[ti][tj] = __builtin_amdgcn_mfma_f32_16x16x32_f16(ah, bl[tj], acc[ti][tj], 0, 0, 0);
                }
            }
        }

        // fold P against fp32 op: C layout: i = m16 (+tiles), j = kg*4 + reg (+tiles)
#pragma unroll
        for (int tj = 0; tj < 4; ++tj) {
            const int i_abs = i0 + wi * 64 + tj * 16 + m16;
            float s = 0.f;
#pragma unroll
            for (int ti = 0; ti < 4; ++ti) {
                const int jb = j0 + wj * 64 + ti * 16 + kg * 4;
                const float4_t ov = *(const float4_t*)(OP + (size_t)i_abs * HID + jb);
#pragma unroll
                for (int r = 0; r < 4; ++r) s += acc[ti][tj][r] * ov[r];
            }
            p[tj] += s;
        }
    }

    // reduce over kg (lane bits 4,5), then combine the two wj halves
#pragma unroll
    for (int tj = 0; tj < 4; ++tj) {
        p[tj] += __shfl_xor(p[tj], 16);
        p[tj] += __shfl_xor(p[tj], 32);
    }
    if (kg == 0) {
#pragma unroll
        for (int tj = 0; tj < 4; ++tj)
            Dred[wj][wi * 64 + tj * 16 + m16] = p[tj];
    }
    __syncthreads();
    if (tid < 128)
        out[(size_t)b * HID + i0 + tid] = Dred[0][tid] + Dred[1][tid];
}

// in-place row softmax: 128 rows x 768
__global__ __launch_bounds__(768)
void softmax_rows(float* __restrict__ out)
{
    const int row = blockIdx.x;
    const int t = threadIdx.x;
    const int wave = t >> 6, lane = t & 63;
    __shared__ float redm[12];
    __shared__ float reds[12];

    float v = out[(size_t)row * HID + t];

    float m = v;
#pragma unroll
    for (int o = 32; o >= 1; o >>= 1) m = fmaxf(m, __shfl_xor(m, o));
    if (lane == 0) redm[wave] = m;
    __syncthreads();
    if (t == 0) {
        float mm = redm[0];
        for (int w = 1; w < 12; ++w) mm = fmaxf(mm, redm[w]);
        redm[0] = mm;
    }
    __syncthreads();
    m = redm[0];

    const float e = expf(v - m);
    float s = e;
#pragma unroll
    for (int o = 32; o >= 1; o >>= 1) s += __shfl_xor(s, o);
    if (lane == 0) reds[wave] = s;
    __syncthreads();
    if (t == 0) {
        float ss = 0.f;
        for (int w = 0; w < 12; ++w) ss += reds[w];
        reds[0] = ss;
    }
    __syncthreads();
    out[(size_t)row * HID + t] = e / reds[0];
}

extern "C" void kernel_launch(void* const* d_in, const int* in_sizes, int n_in,
                              void* d_out, int out_size, void* d_ws, size_t ws_size,
                              hipStream_t stream)
{
    const float* X  = (const float*)d_in[0];   // [128,768,768] fp32
    const float* OP = (const float*)d_in[1];   // [768,768] fp32
    float* out = (float*)d_out;                // [128,768] fp32
    _Float16* opws = (_Float16*)d_ws;          // 2.36 MB pre-split op

    hipLaunchKernelGGL(split_op, dim3(OP_TILES / 4), dim3(256), 0, stream, OP, opws);
    hipLaunchKernelGGL(diag_quad_kernel, dim3(NB * 6), dim3(256), 0, stream, X, OP, opws, out);
    hipLaunchKernelGGL(softmax_rows, dim3(NB), dim3(768), 0, stream, out);
}

// Round 4
// 632.215 us; speedup vs baseline: 1.3318x; 1.1259x over previous
//
#include <hip/hip_runtime.h>

#define HID 768
#define NB  128

typedef _Float16 half8   __attribute__((ext_vector_type(8)));
typedef __fp16   fp16x2  __attribute__((ext_vector_type(2)));
typedef float    float4_t __attribute__((ext_vector_type(4)));

// ws layout: fp16 hi plane [48 i-tile16][24 kstep][64 lane][8 halves], then lo plane.
#define OP_TILES (48 * 24)
#define OP_PLANE ((size_t)OP_TILES * 64 * 8)   // 1.18 MB per plane

// Pre-split operator into fp16 hi/lo, fragment-major (B-operand order).
__global__ __launch_bounds__(256)
void split_op(const float* __restrict__ OP, _Float16* __restrict__ ws)
{
    const int g    = blockIdx.x * 256 + threadIdx.x;
    const int tile = g >> 6, lane = g & 63;
    const int it16 = tile / 24, ks = tile % 24;
    const int i = it16 * 16 + (lane & 15);
    const int k = ks * 32 + (lane >> 4) * 8;
    const float4_t a = *(const float4_t*)(OP + (size_t)i * HID + k);
    const float4_t b = *(const float4_t*)(OP + (size_t)i * HID + k + 4);
    half8 h, l;
#pragma unroll
    for (int e = 0; e < 4; ++e) {
        _Float16 h0 = (_Float16)a[e]; h[e]     = h0; l[e]     = (_Float16)(a[e] - (float)h0);
        _Float16 h1 = (_Float16)b[e]; h[e + 4] = h1; l[e + 4] = (_Float16)(b[e] - (float)h1);
    }
    *(half8*)(ws + (size_t)(tile * 64 + lane) * 8) = h;
    *(half8*)(ws + OP_PLANE + (size_t)(tile * 64 + lane) * 8) = l;
}

__device__ __forceinline__ void convert8(const float4_t a, const float4_t b,
                                         half8& h, half8& l)
{
    // hi = RTZ pack (1 instr / 2 floats); lo = exact residual, RTZ-packed.
    fp16x2 h01 = __builtin_amdgcn_cvt_pkrtz(a[0], a[1]);
    fp16x2 h23 = __builtin_amdgcn_cvt_pkrtz(a[2], a[3]);
    fp16x2 h45 = __builtin_amdgcn_cvt_pkrtz(b[0], b[1]);
    fp16x2 h67 = __builtin_amdgcn_cvt_pkrtz(b[2], b[3]);
    fp16x2 l01 = __builtin_amdgcn_cvt_pkrtz(a[0] - (float)h01[0], a[1] - (float)h01[1]);
    fp16x2 l23 = __builtin_amdgcn_cvt_pkrtz(a[2] - (float)h23[0], a[3] - (float)h23[1]);
    fp16x2 l45 = __builtin_amdgcn_cvt_pkrtz(b[0] - (float)h45[0], b[1] - (float)h45[1]);
    fp16x2 l67 = __builtin_amdgcn_cvt_pkrtz(b[2] - (float)h67[0], b[3] - (float)h67[1]);
    h = (half8){(_Float16)h01[0], (_Float16)h01[1], (_Float16)h23[0], (_Float16)h23[1],
                (_Float16)h45[0], (_Float16)h45[1], (_Float16)h67[0], (_Float16)h67[1]};
    l = (half8){(_Float16)l01[0], (_Float16)l01[1], (_Float16)l23[0], (_Float16)l23[1],
                (_Float16)l45[0], (_Float16)l45[1], (_Float16)l67[0], (_Float16)l67[1]};
}

// D[b,i] = sum_j op[i,j] * P[j,i],  P = X_b @ op^T (k-reduction).
// Block: (b, 128 i) x 128-j tiles; wave: 64j x 64i, acc 4x4 (64 AGPR -> 3 blk/CU).
// A (X) staged in LDS fp16 hi/lo, fragment-major chunks; staging global loads
// use the R0 coalesced map (4 lanes cover one row's contiguous 128 B).
// LDS slot index is XOR-swizzled on BOTH sides (same involution):
//   slot m16' = m16 ^ (kg<<1)   (banks depend only on m16'&7; kg*256B is
//   bank-invariant).  Write phase quad = ((l>>2) ^ 2(l&3))&7 -> Latin square,
//   every bank-quad exactly 2x per 16-lane phase (free).  Read phase: m16' is
//   a permutation per kg-group -> also 2x per quad.  Was 4-way write conflict
//   (4.25e7 cycles) in the R0 identity layout; R3's linear-write map fixed
//   conflicts but broke global coalescing (FETCH +15%, diag 357->463us).
__global__ __launch_bounds__(256, 3)
void diag_quad_kernel(const float* __restrict__ X, const float* __restrict__ OP,
                      const _Float16* __restrict__ opws, float* __restrict__ out)
{
    // chunk (rt,kg,m16'): halves offset rt*512 + kg*128 + m16'*8  (bytes x2)
    __shared__ __align__(16) _Float16 Ah[4096];
    __shared__ __align__(16) _Float16 Al[4096];
    __shared__ float Dred[2][128];

    // XCD swizzle: 6 i-tile blocks of a batch share an XCD (L2 reuse of X_b)
    const int idx  = blockIdx.x;
    const int xcd  = idx & 7, slot = idx >> 3;
    const int b    = xcd * 16 + slot / 6;
    const int it   = slot % 6;
    const int i0   = it * 128;
    const float* Xb = X + (size_t)b * HID * HID;

    const int tid  = threadIdx.x;
    const int lane = tid & 63;
    const int wave = tid >> 6;
    const int wj   = wave & 1;      // j-half (64 rows)
    const int wi   = wave >> 1;     // i-half (64 cols)
    const int m16  = lane & 15;
    const int kg   = lane >> 4;     // 0..3

    // staging: task t (t=tid, tid+256): row=t>>2 (0..127), kgs=t&3; 32B of k per task
    const int row0 = tid >> 2;
    const int kgs  = tid & 3;
    const int m16s = row0 & 15;
    const int swz  = (m16s ^ (kgs << 1)) * 8;              // swizzled slot (write side)
    const int lds0 = (row0 >> 4) * 512 + kgs * 128 + swz;
    const int lds1 = ((row0 + 64) >> 4) * 512 + kgs * 128 + swz;

    const int fragoff  = kg * 128 + (m16 ^ (kg << 1)) * 8;  // + rt*512 (read side, same XOR)
    const int it16base = it * 8 + wi * 4;

    float p[4] = {0.f, 0.f, 0.f, 0.f};

    for (int jt = 0; jt < 6; ++jt) {
        const int j0 = jt * 128;
        float4_t acc[4][4];
#pragma unroll
        for (int a = 0; a < 4; ++a)
#pragma unroll
            for (int c = 0; c < 4; ++c) acc[a][c] = (float4_t){0.f, 0.f, 0.f, 0.f};

        for (int ks = 0; ks < 24; ++ks) {
            const int k0 = ks * 32;

            // B fragments straight from ws (L2) — issue early, no LDS dependency
            half8 bh[4], bl[4];
            const size_t obase = ((size_t)it16base * 24 + ks) * 512 + (size_t)lane * 8;
#pragma unroll
            for (int tj = 0; tj < 4; ++tj) {
                bh[tj] = *(const half8*)(opws + obase + (size_t)tj * 24 * 512);
                bl[tj] = *(const half8*)(opws + OP_PLANE + obase + (size_t)tj * 24 * 512);
            }

            // staging global loads (2 tasks x 32B, coalesced: 4 lanes per row)
            const float* s0 = Xb + (size_t)(j0 + row0) * HID + k0 + kgs * 8;
            const float* s1 = Xb + (size_t)(j0 + row0 + 64) * HID + k0 + kgs * 8;
            const float4_t a0 = *(const float4_t*)(s0);
            const float4_t a1 = *(const float4_t*)(s0 + 4);
            const float4_t b0 = *(const float4_t*)(s1);
            const float4_t b1 = *(const float4_t*)(s1 + 4);
            half8 h0, l0v, h1, l1v;
            convert8(a0, a1, h0, l0v);
            convert8(b0, b1, h1, l1v);

            __syncthreads();   // previous iteration's frag reads complete
            *(half8*)&Ah[lds0] = h0;
            *(half8*)&Al[lds0] = l0v;
            *(half8*)&Ah[lds1] = h1;
            *(half8*)&Al[lds1] = l1v;
            __syncthreads();

#pragma unroll
            for (int ti = 0; ti < 4; ++ti) {
                const int off = (wj * 4 + ti) * 512 + fragoff;
                const half8 ah = *(const half8*)&Ah[off];
                const half8 al = *(const half8*)&Al[off];
#pragma unroll
                for (int tj = 0; tj < 4; ++tj) {
                    acc[ti][tj] = __builtin_amdgcn_mfma_f32_16x16x32_f16(ah, bh[tj], acc[ti][tj], 0, 0, 0);
                    acc[ti][tj] = __builtin_amdgcn_mfma_f32_16x16x32_f16(al, bh[tj], acc[ti][tj], 0, 0, 0);
                    acc[ti][tj] = __builtin_amdgcn_mfma_f32_16x16x32_f16(ah, bl[tj], acc[ti][tj], 0, 0, 0);
                }
            }
        }

        // fold P against fp32 op: C layout: i = m16 (+tiles), j = kg*4 + reg (+tiles)
#pragma unroll
        for (int tj = 0; tj < 4; ++tj) {
            const int i_abs = i0 + wi * 64 + tj * 16 + m16;
            float s = 0.f;
#pragma unroll
            for (int ti = 0; ti < 4; ++ti) {
                const int jb = j0 + wj * 64 + ti * 16 + kg * 4;
                const float4_t ov = *(const float4_t*)(OP + (size_t)i_abs * HID + jb);
#pragma unroll
                for (int r = 0; r < 4; ++r) s += acc[ti][tj][r] * ov[r];
            }
            p[tj] += s;
        }
    }

    // reduce over kg (lane bits 4,5), then combine the two wj halves
#pragma unroll
    for (int tj = 0; tj < 4; ++tj) {
        p[tj] += __shfl_xor(p[tj], 16);
        p[tj] += __shfl_xor(p[tj], 32);
    }
    if (kg == 0) {
#pragma unroll
        for (int tj = 0; tj < 4; ++tj)
            Dred[wj][wi * 64 + tj * 16 + m16] = p[tj];
    }
    __syncthreads();
    if (tid < 128)
        out[(size_t)b * HID + i0 + tid] = Dred[0][tid] + Dred[1][tid];
}

// in-place row softmax: 128 rows x 768
__global__ __launch_bounds__(768)
void softmax_rows(float* __restrict__ out)
{
    const int row = blockIdx.x;
    const int t = threadIdx.x;
    const int wave = t >> 6, lane = t & 63;
    __shared__ float redm[12];
    __shared__ float reds[12];

    float v = out[(size_t)row * HID + t];

    float m = v;
#pragma unroll
    for (int o = 32; o >= 1; o >>= 1) m = fmaxf(m, __shfl_xor(m, o));
    if (lane == 0) redm[wave] = m;
    __syncthreads();
    if (t == 0) {
        float mm = redm[0];
        for (int w = 1; w < 12; ++w) mm = fmaxf(mm, redm[w]);
        redm[0] = mm;
    }
    __syncthreads();
    m = redm[0];

    const float e = expf(v - m);
    float s = e;
#pragma unroll
    for (int o = 32; o >= 1; o >>= 1) s += __shfl_xor(s, o);
    if (lane == 0) reds[wave] = s;
    __syncthreads();
    if (t == 0) {
        float ss = 0.f;
        for (int w = 0; w < 12; ++w) ss += reds[w];
        reds[0] = ss;
    }
    __syncthreads();
    out[(size_t)row * HID + t] = e / reds[0];
}

extern "C" void kernel_launch(void* const* d_in, const int* in_sizes, int n_in,
                              void* d_out, int out_size, void* d_ws, size_t ws_size,
                              hipStream_t stream)
{
    const float* X  = (const float*)d_in[0];   // [128,768,768] fp32
    const float* OP = (const float*)d_in[1];   // [768,768] fp32
    float* out = (float*)d_out;                // [128,768] fp32
    _Float16* opws = (_Float16*)d_ws;          // 2.36 MB pre-split op

    hipLaunchKernelGGL(split_op, dim3(OP_TILES / 4), dim3(256), 0, stream, OP, opws);
    hipLaunchKernelGGL(diag_quad_kernel, dim3(NB * 6), dim3(256), 0, stream, X, OP, opws, out);
    hipLaunchKernelGGL(softmax_rows, dim3(NB), dim3(768), 0, stream, out);
}

// Round 6
// 629.642 us; speedup vs baseline: 1.3373x; 1.0041x over previous
//
#include <hip/hip_runtime.h>

#define HID 768
#define NB  128

typedef _Float16 half8   __attribute__((ext_vector_type(8)));
typedef __fp16   fp16x2  __attribute__((ext_vector_type(2)));
typedef float    float4_t __attribute__((ext_vector_type(4)));

// ws layout: fp16 hi plane [48 i-tile16][24 kstep][64 lane][8 halves], then lo plane.
#define OP_TILES (48 * 24)
#define OP_PLANE ((size_t)OP_TILES * 64 * 8)   // 1.18 MB per plane

// Pre-split operator into fp16 hi/lo, fragment-major (B-operand order).
// (3-term product is required: R5 measured that dropping the op_lo plane
// gives absmax 2.34e-2 > 2e-2 threshold.)
__global__ __launch_bounds__(256)
void split_op(const float* __restrict__ OP, _Float16* __restrict__ ws)
{
    const int g    = blockIdx.x * 256 + threadIdx.x;
    const int tile = g >> 6, lane = g & 63;
    const int it16 = tile / 24, ks = tile % 24;
    const int i = it16 * 16 + (lane & 15);
    const int k = ks * 32 + (lane >> 4) * 8;
    const float4_t a = *(const float4_t*)(OP + (size_t)i * HID + k);
    const float4_t b = *(const float4_t*)(OP + (size_t)i * HID + k + 4);
    half8 h, l;
#pragma unroll
    for (int e = 0; e < 4; ++e) {
        _Float16 h0 = (_Float16)a[e]; h[e]     = h0; l[e]     = (_Float16)(a[e] - (float)h0);
        _Float16 h1 = (_Float16)b[e]; h[e + 4] = h1; l[e + 4] = (_Float16)(b[e] - (float)h1);
    }
    *(half8*)(ws + (size_t)(tile * 64 + lane) * 8) = h;
    *(half8*)(ws + OP_PLANE + (size_t)(tile * 64 + lane) * 8) = l;
}

__device__ __forceinline__ void convert8(const float4_t a, const float4_t b,
                                         half8& h, half8& l)
{
    // hi = RTZ pack (1 instr / 2 floats); lo = exact residual, RTZ-packed.
    fp16x2 h01 = __builtin_amdgcn_cvt_pkrtz(a[0], a[1]);
    fp16x2 h23 = __builtin_amdgcn_cvt_pkrtz(a[2], a[3]);
    fp16x2 h45 = __builtin_amdgcn_cvt_pkrtz(b[0], b[1]);
    fp16x2 h67 = __builtin_amdgcn_cvt_pkrtz(b[2], b[3]);
    fp16x2 l01 = __builtin_amdgcn_cvt_pkrtz(a[0] - (float)h01[0], a[1] - (float)h01[1]);
    fp16x2 l23 = __builtin_amdgcn_cvt_pkrtz(a[2] - (float)h23[0], a[3] - (float)h23[1]);
    fp16x2 l45 = __builtin_amdgcn_cvt_pkrtz(b[0] - (float)h45[0], b[1] - (float)h45[1]);
    fp16x2 l67 = __builtin_amdgcn_cvt_pkrtz(b[2] - (float)h67[0], b[3] - (float)h67[1]);
    h = (half8){(_Float16)h01[0], (_Float16)h01[1], (_Float16)h23[0], (_Float16)h23[1],
                (_Float16)h45[0], (_Float16)h45[1], (_Float16)h67[0], (_Float16)h67[1]};
    l = (half8){(_Float16)l01[0], (_Float16)l01[1], (_Float16)l23[0], (_Float16)l23[1],
                (_Float16)l45[0], (_Float16)l45[1], (_Float16)l67[0], (_Float16)l67[1]};
}

// D[b,i] = sum_j op[i,j] * P[j,i],  P = X_b @ op^T (k-reduction).
// Block: (b, 128 i) x 128-j tiles; wave: 64j x 64i, acc 4x4 (64 AGPR -> 3 blk/CU).
// A (X) staged in LDS fp16 hi/lo, XOR-swizzled slots (R4: conflicts 4.25e7 -> 0,
// both write and read sides free); staging global loads use the coalesced map
// (4 lanes cover one row's contiguous 128 B).
// R6: staging is SOFTWARE-PIPELINED one step ahead inside the unchanged
// 2-barrier structure.  Per step t: B loads(t) -> staging loads(t+1, raw fp32
// in regs) -> MFMA(t) [+fold] -> convert(t+1) -> barrier -> write(t+1) ->
// barrier.  The staging vmcnt wait lands after ~250 cyc of MFMA instead of
// before the barriers, hiding L2 latency; at each __syncthreads vmcnt is
// already drained by the convert, so the implicit vmcnt(0) is free (avoids
// the R1 per-step DMA-drain trap).  Single LDS buffer: writes of t+1 come
// after the barrier that ends all reads of t.
__global__ __launch_bounds__(256, 3)
void diag_quad_kernel(const float* __restrict__ X, const float* __restrict__ OP,
                      const _Float16* __restrict__ opws, float* __restrict__ out)
{
    // chunk (rt,kg,m16'): halves offset rt*512 + kg*128 + m16'*8  (bytes x2)
    __shared__ __align__(16) _Float16 Ah[4096];
    __shared__ __align__(16) _Float16 Al[4096];
    __shared__ float Dred[2][128];

    // XCD swizzle: 6 i-tile blocks of a batch share an XCD (L2 reuse of X_b)
    const int idx  = blockIdx.x;
    const int xcd  = idx & 7, slot = idx >> 3;
    const int b    = xcd * 16 + slot / 6;
    const int it   = slot % 6;
    const int i0   = it * 128;
    const float* Xb = X + (size_t)b * HID * HID;

    const int tid  = threadIdx.x;
    const int lane = tid & 63;
    const int wave = tid >> 6;
    const int wj   = wave & 1;      // j-half (64 rows)
    const int wi   = wave >> 1;     // i-half (64 cols)
    const int m16  = lane & 15;
    const int kg   = lane >> 4;     // 0..3

    // staging: task t (t=tid, tid+256): row=t>>2 (0..127), kgs=t&3; 32B of k per task
    const int row0 = tid >> 2;
    const int kgs  = tid & 3;
    const int m16s = row0 & 15;
    const int swz  = (m16s ^ (kgs << 1)) * 8;              // swizzled slot (write side)
    const int lds0 = (row0 >> 4) * 512 + kgs * 128 + swz;
    const int lds1 = ((row0 + 64) >> 4) * 512 + kgs * 128 + swz;

    const int fragoff  = kg * 128 + (m16 ^ (kg << 1)) * 8;  // + rt*512 (read side, same XOR)
    const int it16base = it * 8 + wi * 4;

    float p[4] = {0.f, 0.f, 0.f, 0.f};

    // prologue: stage (jt=0, ks=0)
    {
        const float* s0 = Xb + (size_t)row0 * HID + kgs * 8;
        const float* s1 = Xb + (size_t)(row0 + 64) * HID + kgs * 8;
        const float4_t a0 = *(const float4_t*)(s0);
        const float4_t a1 = *(const float4_t*)(s0 + 4);
        const float4_t b0 = *(const float4_t*)(s1);
        const float4_t b1 = *(const float4_t*)(s1 + 4);
        half8 h0, l0v, h1, l1v;
        convert8(a0, a1, h0, l0v);
        convert8(b0, b1, h1, l1v);
        *(half8*)&Ah[lds0] = h0;
        *(half8*)&Al[lds0] = l0v;
        *(half8*)&Ah[lds1] = h1;
        *(half8*)&Al[lds1] = l1v;
        __syncthreads();
    }

    float4_t acc[4][4];
    int jt = 0, ks = 0;
    for (int t = 0; t < 144; ++t) {
        const int j0 = jt * 128;

        // B fragments for step t straight from ws (L2) — needed first (MFMA)
        half8 bh[4], bl[4];
        const size_t obase = ((size_t)it16base * 24 + ks) * 512 + (size_t)lane * 8;
#pragma unroll
        for (int tj = 0; tj < 4; ++tj) {
            bh[tj] = *(const half8*)(opws + obase + (size_t)tj * 24 * 512);
            bl[tj] = *(const half8*)(opws + OP_PLANE + obase + (size_t)tj * 24 * 512);
        }

        // issue staging loads for step t+1 (raw fp32; consumed by convert below)
        int kn = ks + 1, jn = jt;
        if (kn == 24) { kn = 0; ++jn; }
        const int jcl = (jn < 6) ? jn : 0;   // final-step dummy prefetch (in-bounds)
        const float* s0 = Xb + (size_t)(jcl * 128 + row0) * HID + kn * 32 + kgs * 8;
        const float* s1 = s0 + (size_t)64 * HID;
        const float4_t a0 = *(const float4_t*)(s0);
        const float4_t a1 = *(const float4_t*)(s0 + 4);
        const float4_t b0 = *(const float4_t*)(s1);
        const float4_t b1 = *(const float4_t*)(s1 + 4);

        if (ks == 0) {
#pragma unroll
            for (int a = 0; a < 4; ++a)
#pragma unroll
                for (int c = 0; c < 4; ++c) acc[a][c] = (float4_t){0.f, 0.f, 0.f, 0.f};
        }

        // MFMA for step t (frags from LDS written last iteration)
#pragma unroll
        for (int ti = 0; ti < 4; ++ti) {
            const int off = (wj * 4 + ti) * 512 + fragoff;
            const half8 ah = *(const half8*)&Ah[off];
            const half8 al = *(const half8*)&Al[off];
#pragma unroll
            for (int tj = 0; tj < 4; ++tj) {
                acc[ti][tj] = __builtin_amdgcn_mfma_f32_16x16x32_f16(ah, bh[tj], acc[ti][tj], 0, 0, 0);
                acc[ti][tj] = __builtin_amdgcn_mfma_f32_16x16x32_f16(al, bh[tj], acc[ti][tj], 0, 0, 0);
                acc[ti][tj] = __builtin_amdgcn_mfma_f32_16x16x32_f16(ah, bl[tj], acc[ti][tj], 0, 0, 0);
            }
        }

        if (ks == 23) {
            // fold P against fp32 op: C layout: i = m16 (+tiles), j = kg*4 + reg
#pragma unroll
            for (int tj = 0; tj < 4; ++tj) {
                const int i_abs = i0 + wi * 64 + tj * 16 + m16;
                float s = 0.f;
#pragma unroll
                for (int ti = 0; ti < 4; ++ti) {
                    const int jb = j0 + wj * 64 + ti * 16 + kg * 4;
                    const float4_t ov = *(const float4_t*)(OP + (size_t)i_abs * HID + jb);
#pragma unroll
                    for (int r = 0; r < 4; ++r) s += acc[ti][tj][r] * ov[r];
                }
                p[tj] += s;
            }
        }

        // convert staged t+1 (vmcnt wait lands here, after the MFMA block)
        half8 h0, l0v, h1, l1v;
        convert8(a0, a1, h0, l0v);
        convert8(b0, b1, h1, l1v);

        __syncthreads();   // all waves' frag reads of step t complete
        *(half8*)&Ah[lds0] = h0;
        *(half8*)&Al[lds0] = l0v;
        *(half8*)&Ah[lds1] = h1;
        *(half8*)&Al[lds1] = l1v;
        __syncthreads();   // step t+1 tile visible

        jt = jn; ks = kn;
    }

    // reduce over kg (lane bits 4,5), then combine the two wj halves
#pragma unroll
    for (int tj = 0; tj < 4; ++tj) {
        p[tj] += __shfl_xor(p[tj], 16);
        p[tj] += __shfl_xor(p[tj], 32);
    }
    if (kg == 0) {
#pragma unroll
        for (int tj = 0; tj < 4; ++tj)
            Dred[wj][wi * 64 + tj * 16 + m16] = p[tj];
    }
    __syncthreads();
    if (tid < 128)
        out[(size_t)b * HID + i0 + tid] = Dred[0][tid] + Dred[1][tid];
}

// in-place row softmax: 128 rows x 768
__global__ __launch_bounds__(768)
void softmax_rows(float* __restrict__ out)
{
    const int row = blockIdx.x;
    const int t = threadIdx.x;
    const int wave = t >> 6, lane = t & 63;
    __shared__ float redm[12];
    __shared__ float reds[12];

    float v = out[(size_t)row * HID + t];

    float m = v;
#pragma unroll
    for (int o = 32; o >= 1; o >>= 1) m = fmaxf(m, __shfl_xor(m, o));
    if (lane == 0) redm[wave] = m;
    __syncthreads();
    if (t == 0) {
        float mm = redm[0];
        for (int w = 1; w < 12; ++w) mm = fmaxf(mm, redm[w]);
        redm[0] = mm;
    }
    __syncthreads();
    m = redm[0];

    const float e = expf(v - m);
    float s = e;
#pragma unroll
    for (int o = 32; o >= 1; o >>= 1) s += __shfl_xor(s, o);
    if (lane == 0) reds[wave] = s;
    __syncthreads();
    if (t == 0) {
        float ss = 0.f;
        for (int w = 0; w < 12; ++w) ss += reds[w];
        reds[0] = ss;
    }
    __syncthreads();
    out[(size_t)row * HID + t] = e / reds[0];
}

extern "C" void kernel_launch(void* const* d_in, const int* in_sizes, int n_in,
                              void* d_out, int out_size, void* d_ws, size_t ws_size,
                              hipStream_t stream)
{
    const float* X  = (const float*)d_in[0];   // [128,768,768] fp32
    const float* OP = (const float*)d_in[1];   // [768,768] fp32
    float* out = (float*)d_out;                // [128,768] fp32
    _Float16* opws = (_Float16*)d_ws;          // 2.36 MB pre-split op

    hipLaunchKernelGGL(split_op, dim3(OP_TILES / 4), dim3(256), 0, stream, OP, opws);
    hipLaunchKernelGGL(diag_quad_kernel, dim3(NB * 6), dim3(256), 0, stream, X, OP, opws, out);
    hipLaunchKernelGGL(softmax_rows, dim3(NB), dim3(768), 0, stream, out);
}